// Round 7
// baseline (1421.333 us; speedup 1.0000x reference)
//
#include <hip/hip_runtime.h>
#include <hip/hip_fp16.h>
#include <math.h>

#define C 16
#define FIN 128

// ---------------- GEMM x@W1 + fused a_s/a_d; h stored fp16 ----------------
__global__ __launch_bounds__(256) void k_gemm1(
    const float* __restrict__ x, const float* __restrict__ W,
    const float* __restrict__ asw, const float* __restrict__ adw,
    __half* __restrict__ h16, float* __restrict__ a_s, float* __restrict__ a_d, int n) {
  __shared__ float xs[64 * 129];
  __shared__ float Ws[FIN * C];
  __shared__ float pAs[4][64], pAd[4][64];
  int t = threadIdx.x;
  int node0 = blockIdx.x * 64;
  for (int i = t; i < FIN * C; i += 256) Ws[i] = W[i];
  for (int i = t; i < 64 * FIN; i += 256) {
    int r = i >> 7, c = i & 127;
    int node = node0 + r;
    xs[r * 129 + c] = (node < n) ? x[(size_t)node * FIN + c] : 0.f;
  }
  __syncthreads();
  int nn = t & 63, cg = (t >> 6) * 4, grp = t >> 6;
  float a0 = 0.f, a1 = 0.f, a2 = 0.f, a3 = 0.f;
  const float* xr = &xs[nn * 129];
  #pragma unroll 8
  for (int k = 0; k < FIN; ++k) {
    float xv = xr[k];
    const float* wr = &Ws[k * C + cg];
    a0 += xv * wr[0]; a1 += xv * wr[1]; a2 += xv * wr[2]; a3 += xv * wr[3];
  }
  int node = node0 + nn;
  if (node < n) {
    __half2 p0 = __floats2half2_rn(a0, a1), p1 = __floats2half2_rn(a2, a3);
    uint2 wv;
    memcpy(&wv.x, &p0, 4); memcpy(&wv.y, &p1, 4);
    *(uint2*)&h16[(size_t)node * C + cg] = wv;
  }
  pAs[grp][nn] = a0 * asw[cg] + a1 * asw[cg + 1] + a2 * asw[cg + 2] + a3 * asw[cg + 3];
  pAd[grp][nn] = a0 * adw[cg] + a1 * adw[cg + 1] + a2 * adw[cg + 2] + a3 * adw[cg + 3];
  __syncthreads();
  if (t < 64 && node0 + t < n) {
    a_s[node0 + t] = pAs[0][t] + pAs[1][t] + pAs[2][t] + pAs[3][t];
    a_d[node0 + t] = pAd[0][t] + pAd[1][t] + pAd[2][t] + pAd[3][t];
  }
}

// ---------------- tiny prep: We·ae dot for both layers ----------------
__global__ void k_prep(const float* __restrict__ We1, const float* __restrict__ ae1,
                       const float* __restrict__ We2, const float* __restrict__ ae2,
                       float* __restrict__ wep) {
  if (threadIdx.x == 0) {
    float a = 0.f, b = 0.f, c = 0.f, d = 0.f;
    for (int i = 0; i < C; ++i) {
      a += We1[i] * ae1[i]; b += We1[C + i] * ae1[i];
      c += We2[i] * ae2[i]; d += We2[C + i] * ae2[i];
    }
    wep[0] = a; wep[1] = b; wep[2] = c; wep[3] = d;
  }
}

// ---------------- CSR build ----------------
__global__ __launch_bounds__(256) void k_hist_rank(
    const int* __restrict__ dst, int* __restrict__ counts,
    int* __restrict__ rank, int ne) {
  int e = blockIdx.x * 256 + threadIdx.x;
  if (e < ne) rank[e] = atomicAdd(&counts[dst[e]], 1);
}

__global__ __launch_bounds__(512) void k_scan1(const int* __restrict__ counts,
                                               int* __restrict__ bsum, int n) {
  __shared__ int sd[512];
  int i = blockIdx.x * 512 + threadIdx.x;
  sd[threadIdx.x] = (i < n) ? counts[i] : 0;
  __syncthreads();
  for (int s = 256; s > 0; s >>= 1) {
    if (threadIdx.x < s) sd[threadIdx.x] += sd[threadIdx.x + s];
    __syncthreads();
  }
  if (threadIdx.x == 0) bsum[blockIdx.x] = sd[0];
}

__global__ __launch_bounds__(512) void k_scan2(int* __restrict__ bsum,
                                               int* __restrict__ offs,
                                               int nblk, int n) {
  __shared__ int sd[512];
  int t = threadIdx.x;
  int v = (t < nblk) ? bsum[t] : 0;
  sd[t] = v;
  __syncthreads();
  for (int off = 1; off < 512; off <<= 1) {
    int x = (t >= off) ? sd[t - off] : 0;
    __syncthreads();
    sd[t] += x;
    __syncthreads();
  }
  if (t < nblk) bsum[t] = sd[t] - v;
  if (t == nblk - 1) offs[n] = sd[t];
}

__global__ __launch_bounds__(512) void k_scan3(const int* __restrict__ counts,
                                               const int* __restrict__ bsum,
                                               int* __restrict__ offs, int n) {
  __shared__ int sd[512];
  int t = threadIdx.x;
  int i = blockIdx.x * 512 + t;
  int v = (i < n) ? counts[i] : 0;
  sd[t] = v;
  __syncthreads();
  for (int off = 1; off < 512; off <<= 1) {
    int x = (t >= off) ? sd[t - off] : 0;
    __syncthreads();
    sd[t] += x;
    __syncthreads();
  }
  if (i < n) offs[i] = bsum[blockIdx.x] + sd[t] - v;
}

// scatter + layer-1 edge softmax numerator: ebuf = {src, ex1, ea_half2, dst}
__global__ __launch_bounds__(256) void k_scatter(
    const int* __restrict__ src, const int* __restrict__ dst,
    const float2* __restrict__ ea, const int* __restrict__ offs,
    const int* __restrict__ rank,
    const float* __restrict__ a_s, const float* __restrict__ a_d,
    const float* __restrict__ wep,
    uint4* __restrict__ ebuf, int ne) {
  int e = blockIdx.x * 256 + threadIdx.x;
  if (e >= ne) return;
  int s = src[e], d = dst[e];
  float2 a = ea[e];
  float lg = a_s[s] + a_d[d] + a.x * wep[0] + a.y * wep[1];
  lg = lg > 0.f ? lg : 0.2f * lg;
  float ex = __expf(lg);
  __half2 hh = __floats2half2_rn(a.x, a.y);
  unsigned int hb;
  memcpy(&hb, &hh, 4);
  ebuf[offs[d] + rank[e]] =
      make_uint4((unsigned int)s, __float_as_uint(ex), hb, (unsigned int)d);
}

// layer-2 edge softmax numerator, in place (slot-parallel, coalesced)
__global__ __launch_bounds__(256) void k_exp2(
    uint4* __restrict__ ebuf,
    const float* __restrict__ a_s, const float* __restrict__ a_d,
    const float* __restrict__ wep2, int ne) {
  int e = blockIdx.x * 256 + threadIdx.x;
  if (e >= ne) return;
  uint4 r = ebuf[e];
  __half2 hh;
  memcpy(&hh, &r.z, 4);
  float2 eaf = __half22float2(hh);
  float lg = a_s[(int)r.x] + a_d[(int)r.w] + eaf.x * wep2[0] + eaf.y * wep2[1];
  lg = lg > 0.f ? lg : 0.2f * lg;
  ebuf[e].y = __float_as_uint(__expf(lg));
}

// ---- gather L1: one wave per node; lane = sub*16 + channel; 4-way edge split ----
__global__ __launch_bounds__(256) void k_gather1(
    const uint4* __restrict__ ebuf, const int* __restrict__ offs,
    const float* __restrict__ a_s, const float* __restrict__ a_d,
    const __half* __restrict__ h16,
    const float* __restrict__ wep, const float* __restrict__ bias,
    float* __restrict__ outv, float2* __restrict__ laxlay,
    float* __restrict__ bnsum, float* __restrict__ bnsq, int n) {
  __shared__ float sbn[32];
  int t = threadIdx.x;
  if (t < 32) sbn[t] = 0.f;
  __syncthreads();

  int node = blockIdx.x * 4 + (t >> 6);
  int l = t & 15, sub = (t >> 4) & 3;
  float v = 0.f;
  if (node < n) {
    int o0 = offs[node], o1 = offs[node + 1];
    float acc = 0.f, den = 0.f, lax = 0.f, lay = 0.f;
    for (int e = o0 + sub; e < o1; e += 4) {
      uint4 r = ebuf[e];
      float ex = __uint_as_float(r.y);
      __half2 hh;
      memcpy(&hh, &r.z, 4);
      float2 eaf = __half22float2(hh);
      den += ex; lax += eaf.x; lay += eaf.y;
      acc += ex * __half2float(h16[(size_t)r.x * C + l]);
    }
    acc += __shfl_xor(acc, 32); acc += __shfl_xor(acc, 16);
    den += __shfl_xor(den, 32); den += __shfl_xor(den, 16);
    lax += __shfl_xor(lax, 32); lax += __shfl_xor(lax, 16);
    lay += __shfl_xor(lay, 32); lay += __shfl_xor(lay, 16);
    if (sub == 0) {
      float dgc = fmaxf((float)(o1 - o0), 1.f);
      float lg = a_s[node] + a_d[node] + (lax * wep[0] + lay * wep[1]) / dgc;
      lg = lg > 0.f ? lg : 0.2f * lg;
      float ex = __expf(lg);
      float hi = __half2float(h16[(size_t)node * C + l]);
      v = fmaxf((acc + ex * hi) / (den + ex) + bias[l], 0.f);
      outv[(size_t)node * C + l] = v;
      if (l == 0) laxlay[node] = make_float2(lax, lay);
    }
  }
  if ((t & 63) < 16) {
    atomicAdd(&sbn[l], v);
    atomicAdd(&sbn[16 + l], v * v);
  }
  __syncthreads();
  if (t < 16) atomicAdd(&bnsum[t], sbn[t]);
  else if (t < 32) atomicAdd(&bnsq[t - 16], sbn[t]);
}

// ---- gather L2: same shape, ex precomputed by k_exp2, laxlay reused ----
__global__ __launch_bounds__(256) void k_gather2(
    const uint4* __restrict__ ebuf, const int* __restrict__ offs,
    const float* __restrict__ a_s, const float* __restrict__ a_d,
    const __half* __restrict__ h16,
    const float* __restrict__ wep, const float* __restrict__ bias,
    const float2* __restrict__ laxlay,
    float* __restrict__ outv, int n) {
  int t = threadIdx.x;
  int node = blockIdx.x * 4 + (t >> 6);
  if (node >= n) return;
  int l = t & 15, sub = (t >> 4) & 3;
  int o0 = offs[node], o1 = offs[node + 1];
  float acc = 0.f, den = 0.f;
  for (int e = o0 + sub; e < o1; e += 4) {
    uint4 r = ebuf[e];
    float ex = __uint_as_float(r.y);
    den += ex;
    acc += ex * __half2float(h16[(size_t)r.x * C + l]);
  }
  acc += __shfl_xor(acc, 32); acc += __shfl_xor(acc, 16);
  den += __shfl_xor(den, 32); den += __shfl_xor(den, 16);
  if (sub == 0) {
    float2 ll = laxlay[node];
    float dgc = fmaxf((float)(o1 - o0), 1.f);
    float lg = a_s[node] + a_d[node] + (ll.x * wep[0] + ll.y * wep[1]) / dgc;
    lg = lg > 0.f ? lg : 0.2f * lg;
    float ex = __expf(lg);
    float hi = __half2float(h16[(size_t)node * C + l]);
    float v = fmaxf((acc + ex * hi) / (den + ex) + bias[l], 0.f);
    outv[(size_t)node * C + l] = v;
  }
}

__global__ void k_bnp(const float* __restrict__ bnsum, const float* __restrict__ bnsq,
                      const float* __restrict__ g, const float* __restrict__ bb,
                      float* __restrict__ scale, float* __restrict__ shift, float invn) {
  int c = threadIdx.x;
  if (c >= C) return;
  float mean = bnsum[c] * invn;
  float var = bnsq[c] * invn - mean * mean;
  float s = g[c] * rsqrtf(var + 1e-5f);
  scale[c] = s; shift[c] = bb[c] - mean * s;
}

// ---------------- BN + 16x16 matmul + a_s/a_d for layer 2; h out fp16 ----------------
__global__ __launch_bounds__(256) void k_node2(
    const float* __restrict__ outv, const float* __restrict__ scale,
    const float* __restrict__ shift, const float* __restrict__ W2,
    const float* __restrict__ asw, const float* __restrict__ adw,
    __half* __restrict__ h16, float* __restrict__ a_s, float* __restrict__ a_d, int n) {
  __shared__ float w2s[C * C];
  if (threadIdx.x < C * C) w2s[threadIdx.x] = W2[threadIdx.x];
  __syncthreads();
  int i = blockIdx.x * 256 + threadIdx.x;
  if (i >= n) return;
  float hn[C];
  #pragma unroll
  for (int c = 0; c < C; ++c) hn[c] = outv[(size_t)i * C + c] * scale[c] + shift[c];
  float h2[C];
  #pragma unroll
  for (int j = 0; j < C; ++j) {
    float acc = 0.f;
    #pragma unroll
    for (int c = 0; c < C; ++c) acc += hn[c] * w2s[c * C + j];
    h2[j] = acc;
  }
  float hs = 0.f, hd = 0.f;
  #pragma unroll
  for (int j = 0; j < C; ++j) { hs += h2[j] * asw[j]; hd += h2[j] * adw[j]; }
  a_s[i] = hs; a_d[i] = hd;
  union { uint4 u; __half2 p[4]; } A, Bu;
  A.p[0] = __floats2half2_rn(h2[0], h2[1]);  A.p[1] = __floats2half2_rn(h2[2], h2[3]);
  A.p[2] = __floats2half2_rn(h2[4], h2[5]);  A.p[3] = __floats2half2_rn(h2[6], h2[7]);
  Bu.p[0] = __floats2half2_rn(h2[8], h2[9]);  Bu.p[1] = __floats2half2_rn(h2[10], h2[11]);
  Bu.p[2] = __floats2half2_rn(h2[12], h2[13]); Bu.p[3] = __floats2half2_rn(h2[14], h2[15]);
  uint4* hp = (uint4*)(h16 + (size_t)i * C);
  hp[0] = A.u; hp[1] = Bu.u;
}

// ---------------- graph segment offsets ----------------
__global__ void k_gstart(const int* __restrict__ batch, int* __restrict__ gs,
                         int n, int B_) {
  int g = blockIdx.x * blockDim.x + threadIdx.x;
  if (g > B_) return;
  if (g == B_) { gs[B_] = n; return; }
  int lo = 0, hi = n;
  while (lo < hi) { int mid = (lo + hi) >> 1; if (batch[mid] < g) lo = mid + 1; else hi = mid; }
  gs[g] = lo;
}

__global__ __launch_bounds__(256) void k_xe(
    const float* __restrict__ outv, const int* __restrict__ gs,
    float* __restrict__ xe, int B_) {
  int wave = blockIdx.x * 4 + (threadIdx.x >> 6);
  if (wave >= B_) return;
  int lane = threadIdx.x & 63;
  int c = lane & 15, sub = lane >> 4;
  int base = gs[wave], end = gs[wave + 1];
  float s = 0.f;
  for (int n0 = base + sub; n0 < end; n0 += 4) s += outv[(size_t)n0 * C + c];
  s += __shfl_down(s, 32);
  s += __shfl_down(s, 16);
  if (lane < 16) xe[(size_t)wave * C + c] = s / fmaxf((float)(end - base), 1.f);
}

// ---------------- D2RL tail: BN/MLP stages only ----------------
__global__ __launch_bounds__(512) void k_tail_z3(
    const float* __restrict__ xe_in,
    const float* __restrict__ gL1, const float* __restrict__ bL1,
    const float* __restrict__ Wl1, const float* __restrict__ bl1,
    const float* __restrict__ gL2, const float* __restrict__ bL2,
    const float* __restrict__ Wl2, const float* __restrict__ bl2,
    const float* __restrict__ gL3, const float* __restrict__ bL3,
    const float* __restrict__ Wl3, const float* __restrict__ bl3,
    float* __restrict__ z3buf, int B_) {
  __shared__ float ssum[2 * C], ssq[2 * C], sc[2 * C], sh[2 * C];
  int t = threadIdx.x;
  float invB = 1.f / (float)B_;
  float xe[C];
  #pragma unroll
  for (int c = 0; c < C; ++c) xe[c] = xe_in[(size_t)t * C + c];

  if (t < 2 * C) { ssum[t] = 0.f; ssq[t] = 0.f; }
  __syncthreads();
  #pragma unroll
  for (int c = 0; c < C; ++c) {
    float s = xe[c], q = xe[c] * xe[c];
    for (int o = 32; o > 0; o >>= 1) { s += __shfl_down(s, o); q += __shfl_down(q, o); }
    if ((t & 63) == 0) { atomicAdd(&ssum[c], s); atomicAdd(&ssq[c], q); }
  }
  __syncthreads();
  if (t < C) {
    float mean = ssum[t] * invB, var = ssq[t] * invB - mean * mean;
    float s = gL1[t] * rsqrtf(var + 1e-5f);
    sc[t] = s; sh[t] = bL1[t] - mean * s;
  }
  __syncthreads();
  float z[C];
  #pragma unroll
  for (int j = 0; j < C; ++j) {
    float acc = bl1[j];
    #pragma unroll
    for (int c = 0; c < C; ++c) acc += (xe[c] * sc[c] + sh[c]) * Wl1[c * C + j];
    z[j] = fmaxf(acc, 0.f);
  }
  __syncthreads();

  if (t < 2 * C) { ssum[t] = 0.f; ssq[t] = 0.f; }
  __syncthreads();
  #pragma unroll
  for (int c = 0; c < C; ++c) {
    float s = z[c], q = z[c] * z[c];
    for (int o = 32; o > 0; o >>= 1) { s += __shfl_down(s, o); q += __shfl_down(q, o); }
    if ((t & 63) == 0) { atomicAdd(&ssum[c], s); atomicAdd(&ssq[c], q); }
    float s2 = xe[c], q2 = xe[c] * xe[c];
    for (int o = 32; o > 0; o >>= 1) { s2 += __shfl_down(s2, o); q2 += __shfl_down(q2, o); }
    if ((t & 63) == 0) { atomicAdd(&ssum[C + c], s2); atomicAdd(&ssq[C + c], q2); }
  }
  __syncthreads();
  if (t < 2 * C) {
    float mean = ssum[t] * invB, var = ssq[t] * invB - mean * mean;
    float s = gL2[t] * rsqrtf(var + 1e-5f);
    sc[t] = s; sh[t] = bL2[t] - mean * s;
  }
  __syncthreads();
  float z2[C];
  #pragma unroll
  for (int j = 0; j < C; ++j) {
    float acc = bl2[j];
    #pragma unroll
    for (int c = 0; c < C; ++c) acc += (z[c] * sc[c] + sh[c]) * Wl2[c * C + j];
    #pragma unroll
    for (int c = 0; c < C; ++c) acc += (xe[c] * sc[C + c] + sh[C + c]) * Wl2[(C + c) * C + j];
    z2[j] = fmaxf(acc, 0.f);
  }
  __syncthreads();

  if (t < 2 * C) { ssum[t] = 0.f; ssq[t] = 0.f; }
  __syncthreads();
  #pragma unroll
  for (int c = 0; c < C; ++c) {
    float s = z2[c], q = z2[c] * z2[c];
    for (int o = 32; o > 0; o >>= 1) { s += __shfl_down(s, o); q += __shfl_down(q, o); }
    if ((t & 63) == 0) { atomicAdd(&ssum[c], s); atomicAdd(&ssq[c], q); }
    float s2 = xe[c], q2 = xe[c] * xe[c];
    for (int o = 32; o > 0; o >>= 1) { s2 += __shfl_down(s2, o); q2 += __shfl_down(q2, o); }
    if ((t & 63) == 0) { atomicAdd(&ssum[C + c], s2); atomicAdd(&ssq[C + c], q2); }
  }
  __syncthreads();
  if (t < 2 * C) {
    float mean = ssum[t] * invB, var = ssq[t] * invB - mean * mean;
    float s = gL3[t] * rsqrtf(var + 1e-5f);
    sc[t] = s; sh[t] = bL3[t] - mean * s;
  }
  __syncthreads();
  #pragma unroll
  for (int j = 0; j < C; ++j) {
    float acc = bl3[j];
    #pragma unroll
    for (int c = 0; c < C; ++c) acc += (z2[c] * sc[c] + sh[c]) * Wl3[c * C + j];
    #pragma unroll
    for (int c = 0; c < C; ++c) acc += (xe[c] * sc[C + c] + sh[C + c]) * Wl3[(C + c) * C + j];
    z3buf[(size_t)t * C + j] = fmaxf(acc, 0.f);
  }
}

// ---------------- heads: one wave per graph ----------------
__global__ __launch_bounds__(256) void k_heads(
    const float* __restrict__ z3buf,
    const float* __restrict__ Wx, const float* __restrict__ bx,
    const float* __restrict__ Wy, const float* __restrict__ by,
    const float* __restrict__ Wr, const float* __restrict__ br,
    float* __restrict__ out, int B_) {
  int wv = blockIdx.x * 4 + (threadIdx.x >> 6);
  if (wv >= B_) return;
  int lane = threadIdx.x & 63;
  float z[C];
  #pragma unroll
  for (int c = 0; c < C; ++c) z[c] = z3buf[(size_t)wv * C + c];

  float ax = bx[lane];
  #pragma unroll
  for (int c = 0; c < C; ++c) ax += z[c] * Wx[c * 64 + lane];
  float m = ax;
  #pragma unroll
  for (int o = 32; o > 0; o >>= 1) m = fmaxf(m, __shfl_xor(m, o));
  float e = __expf(ax - m);
  float s = e;
  #pragma unroll
  for (int o = 32; o > 0; o >>= 1) s += __shfl_xor(s, o);
  out[(size_t)wv * 64 + lane] = e / s;

  float ay = by[lane];
  #pragma unroll
  for (int c = 0; c < C; ++c) ay += z[c] * Wy[c * 64 + lane];
  m = ay;
  #pragma unroll
  for (int o = 32; o > 0; o >>= 1) m = fmaxf(m, __shfl_xor(m, o));
  e = __expf(ay - m);
  s = e;
  #pragma unroll
  for (int o = 32; o > 0; o >>= 1) s += __shfl_xor(s, o);
  out[(size_t)B_ * 64 + (size_t)wv * 64 + lane] = e / s;

  if (lane < 4) {
    float ar = br[lane];
    #pragma unroll
    for (int c = 0; c < C; ++c) ar += z[c] * Wr[c * 4 + lane];
    float mr = ar;
    mr = fmaxf(mr, __shfl_xor(mr, 1));
    mr = fmaxf(mr, __shfl_xor(mr, 2));
    float er = __expf(ar - mr);
    float sr = er;
    sr += __shfl_xor(sr, 1);
    sr += __shfl_xor(sr, 2);
    out[(size_t)B_ * 128 + (size_t)wv * 4 + lane] = er / sr;
  }
}

extern "C" void kernel_launch(void* const* d_in, const int* in_sizes, int n_in,
                              void* d_out, int out_size, void* d_ws, size_t ws_size,
                              hipStream_t stream) {
  const float* x     = (const float*)d_in[0];
  const int*   eidx  = (const int*)d_in[1];
  const float* eattr = (const float*)d_in[2];
  const int*   batch = (const int*)d_in[3];
  const float* W1  = (const float*)d_in[4];
  const float* We1 = (const float*)d_in[5];
  const float* as1 = (const float*)d_in[6];
  const float* ad1 = (const float*)d_in[7];
  const float* ae1 = (const float*)d_in[8];
  const float* b1  = (const float*)d_in[9];
  const float* g1  = (const float*)d_in[10];
  const float* bb1 = (const float*)d_in[11];
  const float* W2  = (const float*)d_in[12];
  const float* We2 = (const float*)d_in[13];
  const float* as2 = (const float*)d_in[14];
  const float* ad2 = (const float*)d_in[15];
  const float* ae2 = (const float*)d_in[16];
  const float* b2  = (const float*)d_in[17];
  const float* gL1 = (const float*)d_in[18];
  const float* bL1 = (const float*)d_in[19];
  const float* Wl1 = (const float*)d_in[20];
  const float* bl1 = (const float*)d_in[21];
  const float* gL2 = (const float*)d_in[22];
  const float* bL2 = (const float*)d_in[23];
  const float* Wl2 = (const float*)d_in[24];
  const float* bl2 = (const float*)d_in[25];
  const float* gL3 = (const float*)d_in[26];
  const float* bL3 = (const float*)d_in[27];
  const float* Wl3 = (const float*)d_in[28];
  const float* bl3 = (const float*)d_in[29];
  const float* Wx  = (const float*)d_in[30];
  const float* bx  = (const float*)d_in[31];
  const float* Wy  = (const float*)d_in[32];
  const float* by  = (const float*)d_in[33];
  const float* Wr  = (const float*)d_in[34];
  const float* br  = (const float*)d_in[35];

  int N = in_sizes[3];
  int E = in_sizes[2] / 2;
  int B = out_size / 132;
  int nblk = (N + 511) / 512;

  char* w = (char*)d_ws;
  size_t o = 0;
  auto alloc = [&](size_t bytes) { char* p = w + o; o += (bytes + 15) & ~15ull; return p; };
  uint4*  ebuf   = (uint4*)alloc((size_t)E * 16);
  int*    rank   = (int*)alloc((size_t)E * 4);
  __half* h16    = (__half*)alloc((size_t)N * C * 2);
  float*  outv   = (float*)alloc((size_t)N * C * 4);
  float*  a_s    = (float*)alloc((size_t)N * 4);
  float*  a_d    = (float*)alloc((size_t)N * 4);
  float2* laxlay = (float2*)alloc((size_t)N * 8);
  int*    counts = (int*)alloc((size_t)N * 4);
  int*    offs   = (int*)alloc((size_t)(N + 4) * 4);
  int*    bsum   = (int*)alloc((size_t)(nblk + 4) * 4);
  float*  bn     = (float*)alloc(64 * 4);
  float*  wep    = (float*)alloc(16 * 4);
  float*  xe     = (float*)alloc((size_t)B * C * 4);
  int*    gs     = (int*)alloc((size_t)(B + 4) * 4);
  float*  z3buf  = (float*)alloc((size_t)B * C * 4);

  const int* src = eidx;
  const int* dst = eidx + E;
  int ebl = (E + 255) / 256;
  int nbl = (N + 255) / 256;
  int gbl = (N + 3) / 4;

  hipMemsetAsync(counts, 0, (size_t)N * 4, stream);
  hipMemsetAsync(bn, 0, 32 * 4, stream);

  k_prep<<<1, 64, 0, stream>>>(We1, ae1, We2, ae2, wep);
  k_gemm1<<<(N + 63) / 64, 256, 0, stream>>>(x, W1, as1, ad1, h16, a_s, a_d, N);
  k_hist_rank<<<ebl, 256, 0, stream>>>(dst, counts, rank, E);
  k_scan1<<<nblk, 512, 0, stream>>>(counts, bsum, N);
  k_scan2<<<1, 512, 0, stream>>>(bsum, offs, nblk, N);
  k_scan3<<<nblk, 512, 0, stream>>>(counts, bsum, offs, N);
  k_scatter<<<ebl, 256, 0, stream>>>(src, dst, (const float2*)eattr, offs, rank,
                                     a_s, a_d, wep, ebuf, E);
  k_gather1<<<gbl, 256, 0, stream>>>(ebuf, offs, a_s, a_d, h16, wep, b1,
                                     outv, laxlay, bn, bn + 16, N);
  k_bnp<<<1, 64, 0, stream>>>(bn, bn + 16, g1, bb1, bn + 32, bn + 48, 1.f / (float)N);
  k_node2<<<nbl, 256, 0, stream>>>(outv, bn + 32, bn + 48, W2, as2, ad2, h16, a_s, a_d, N);
  k_exp2<<<ebl, 256, 0, stream>>>(ebuf, a_s, a_d, wep + 2, E);
  k_gather2<<<gbl, 256, 0, stream>>>(ebuf, offs, a_s, a_d, h16, wep + 2, b2,
                                     laxlay, outv, N);
  k_gstart<<<(B + 1 + 255) / 256, 256, 0, stream>>>(batch, gs, N, B);
  k_xe<<<(B + 3) / 4, 256, 0, stream>>>(outv, gs, xe, B);
  k_tail_z3<<<1, B, 0, stream>>>(xe, gL1, bL1, Wl1, bl1, gL2, bL2, Wl2, bl2,
                                 gL3, bL3, Wl3, bl3, z3buf, B);
  k_heads<<<(B + 3) / 4, 256, 0, stream>>>(z3buf, Wx, bx, Wy, by, Wr, br,
                                           (float*)d_out, B);
}

// Round 8
// 979.547 us; speedup vs baseline: 1.4510x; 1.4510x over previous
//
#include <hip/hip_runtime.h>
#include <hip/hip_fp16.h>
#include <math.h>

#define C 16
#define FIN 128

__device__ __forceinline__ float hld(const __half* __restrict__ h16, unsigned int s, int l) {
  return __half2float(h16[(size_t)s * C + l]);
}

// ---------------- GEMM x@W1 + fused a_s/a_d; h stored fp16 ----------------
__global__ __launch_bounds__(256) void k_gemm1(
    const float* __restrict__ x, const float* __restrict__ W,
    const float* __restrict__ asw, const float* __restrict__ adw,
    __half* __restrict__ h16, float* __restrict__ a_s, float* __restrict__ a_d, int n) {
  __shared__ float xs[64 * 129];
  __shared__ float Ws[FIN * C];
  __shared__ float pAs[4][64], pAd[4][64];
  int t = threadIdx.x;
  int node0 = blockIdx.x * 64;
  for (int i = t; i < FIN * C; i += 256) Ws[i] = W[i];
  for (int i = t; i < 64 * FIN; i += 256) {
    int r = i >> 7, c = i & 127;
    int node = node0 + r;
    xs[r * 129 + c] = (node < n) ? x[(size_t)node * FIN + c] : 0.f;
  }
  __syncthreads();
  int nn = t & 63, cg = (t >> 6) * 4, grp = t >> 6;
  float a0 = 0.f, a1 = 0.f, a2 = 0.f, a3 = 0.f;
  const float* xr = &xs[nn * 129];
  #pragma unroll 8
  for (int k = 0; k < FIN; ++k) {
    float xv = xr[k];
    const float* wr = &Ws[k * C + cg];
    a0 += xv * wr[0]; a1 += xv * wr[1]; a2 += xv * wr[2]; a3 += xv * wr[3];
  }
  int node = node0 + nn;
  if (node < n) {
    __half2 p0 = __floats2half2_rn(a0, a1), p1 = __floats2half2_rn(a2, a3);
    uint2 wv;
    memcpy(&wv.x, &p0, 4); memcpy(&wv.y, &p1, 4);
    *(uint2*)&h16[(size_t)node * C + cg] = wv;
  }
  pAs[grp][nn] = a0 * asw[cg] + a1 * asw[cg + 1] + a2 * asw[cg + 2] + a3 * asw[cg + 3];
  pAd[grp][nn] = a0 * adw[cg] + a1 * adw[cg + 1] + a2 * adw[cg + 2] + a3 * adw[cg + 3];
  __syncthreads();
  if (t < 64 && node0 + t < n) {
    a_s[node0 + t] = pAs[0][t] + pAs[1][t] + pAs[2][t] + pAs[3][t];
    a_d[node0 + t] = pAd[0][t] + pAd[1][t] + pAd[2][t] + pAd[3][t];
  }
}

// ---------------- tiny prep: We·ae dot for both layers ----------------
__global__ void k_prep(const float* __restrict__ We1, const float* __restrict__ ae1,
                       const float* __restrict__ We2, const float* __restrict__ ae2,
                       float* __restrict__ wep) {
  if (threadIdx.x == 0) {
    float a = 0.f, b = 0.f, c = 0.f, d = 0.f;
    for (int i = 0; i < C; ++i) {
      a += We1[i] * ae1[i]; b += We1[C + i] * ae1[i];
      c += We2[i] * ae2[i]; d += We2[C + i] * ae2[i];
    }
    wep[0] = a; wep[1] = b; wep[2] = c; wep[3] = d;
  }
}

// ---------------- CSR build ----------------
__global__ __launch_bounds__(256) void k_hist_rank(
    const int* __restrict__ dst, int* __restrict__ counts,
    int* __restrict__ rank, int ne) {
  int e = blockIdx.x * 256 + threadIdx.x;
  if (e < ne) rank[e] = atomicAdd(&counts[dst[e]], 1);
}

__global__ __launch_bounds__(512) void k_scan1(const int* __restrict__ counts,
                                               int* __restrict__ bsum, int n) {
  __shared__ int sd[512];
  int i = blockIdx.x * 512 + threadIdx.x;
  sd[threadIdx.x] = (i < n) ? counts[i] : 0;
  __syncthreads();
  for (int s = 256; s > 0; s >>= 1) {
    if (threadIdx.x < s) sd[threadIdx.x] += sd[threadIdx.x + s];
    __syncthreads();
  }
  if (threadIdx.x == 0) bsum[blockIdx.x] = sd[0];
}

__global__ __launch_bounds__(512) void k_scan2(int* __restrict__ bsum,
                                               int* __restrict__ offs,
                                               int nblk, int n) {
  __shared__ int sd[512];
  int t = threadIdx.x;
  int v = (t < nblk) ? bsum[t] : 0;
  sd[t] = v;
  __syncthreads();
  for (int off = 1; off < 512; off <<= 1) {
    int x = (t >= off) ? sd[t - off] : 0;
    __syncthreads();
    sd[t] += x;
    __syncthreads();
  }
  if (t < nblk) bsum[t] = sd[t] - v;
  if (t == nblk - 1) offs[n] = sd[t];
}

__global__ __launch_bounds__(512) void k_scan3(const int* __restrict__ counts,
                                               const int* __restrict__ bsum,
                                               int* __restrict__ offs, int n) {
  __shared__ int sd[512];
  int t = threadIdx.x;
  int i = blockIdx.x * 512 + t;
  int v = (i < n) ? counts[i] : 0;
  sd[t] = v;
  __syncthreads();
  for (int off = 1; off < 512; off <<= 1) {
    int x = (t >= off) ? sd[t - off] : 0;
    __syncthreads();
    sd[t] += x;
    __syncthreads();
  }
  if (i < n) offs[i] = bsum[blockIdx.x] + sd[t] - v;
}

// scatter: eb[slot]={src, ex1}, eaw[slot]=half2(ea), dstb[slot]=dst
__global__ __launch_bounds__(256) void k_scatter(
    const int* __restrict__ src, const int* __restrict__ dst,
    const float2* __restrict__ ea, const int* __restrict__ offs,
    const int* __restrict__ rank,
    const float* __restrict__ a_s, const float* __restrict__ a_d,
    const float* __restrict__ wep,
    uint2* __restrict__ eb, unsigned int* __restrict__ eaw,
    int* __restrict__ dstb, int ne) {
  int e = blockIdx.x * 256 + threadIdx.x;
  if (e >= ne) return;
  int s = src[e], d = dst[e];
  float2 a = ea[e];
  float lg = a_s[s] + a_d[d] + a.x * wep[0] + a.y * wep[1];
  lg = lg > 0.f ? lg : 0.2f * lg;
  float ex = __expf(lg);
  __half2 hh = __floats2half2_rn(a.x, a.y);
  unsigned int hb;
  memcpy(&hb, &hh, 4);
  int slot = offs[d] + rank[e];
  eb[slot] = make_uint2((unsigned int)s, __float_as_uint(ex));
  eaw[slot] = hb;
  dstb[slot] = d;
}

// layer-2 edge numerator in place (slot-parallel, coalesced streams + 2 gathers)
__global__ __launch_bounds__(256) void k_exp2(
    uint2* __restrict__ eb, const unsigned int* __restrict__ eaw,
    const int* __restrict__ dstb,
    const float* __restrict__ a_s, const float* __restrict__ a_d,
    const float* __restrict__ wep2, int ne) {
  int e = blockIdx.x * 256 + threadIdx.x;
  if (e >= ne) return;
  uint2 r = eb[e];
  __half2 hh;
  memcpy(&hh, &eaw[e], 4);
  float2 eaf = __half22float2(hh);
  float lg = a_s[(int)r.x] + a_d[dstb[e]] + eaf.x * wep2[0] + eaf.y * wep2[1];
  lg = lg > 0.f ? lg : 0.2f * lg;
  eb[e].y = __float_as_uint(__expf(lg));
}

// ---- gather L1: 16 lanes/node broadcast form, manual 4x unroll ----
__global__ __launch_bounds__(256) void k_gather1(
    const uint2* __restrict__ eb, const unsigned int* __restrict__ eaw,
    const int* __restrict__ offs,
    const float* __restrict__ a_s, const float* __restrict__ a_d,
    const __half* __restrict__ h16,
    const float* __restrict__ wep, const float* __restrict__ bias,
    float* __restrict__ outv, float2* __restrict__ laxlay,
    float* __restrict__ bnsum, float* __restrict__ bnsq, int n) {
  __shared__ float sbn[32];
  int t = threadIdx.x;
  if (t < 32) sbn[t] = 0.f;
  __syncthreads();
  int node = blockIdx.x * 16 + (t >> 4);
  int l = t & 15;
  float v = 0.f;
  if (node < n) {
    int o0 = offs[node], o1 = offs[node + 1];
    float A0 = 0.f, A1 = 0.f, A2 = 0.f, A3 = 0.f;
    float D0 = 0.f, D1 = 0.f, D2 = 0.f, D3 = 0.f;
    float lx = 0.f, ly = 0.f;
    int e = o0;
    for (; e + 4 <= o1; e += 4) {
      uint2 r0 = eb[e], r1 = eb[e + 1], r2 = eb[e + 2], r3 = eb[e + 3];
      unsigned int w0 = eaw[e], w1 = eaw[e + 1], w2 = eaw[e + 2], w3 = eaw[e + 3];
      float h0 = hld(h16, r0.x, l), h1 = hld(h16, r1.x, l);
      float h2 = hld(h16, r2.x, l), h3 = hld(h16, r3.x, l);
      float e0 = __uint_as_float(r0.y), e1 = __uint_as_float(r1.y);
      float e2 = __uint_as_float(r2.y), e3 = __uint_as_float(r3.y);
      A0 += e0 * h0; A1 += e1 * h1; A2 += e2 * h2; A3 += e3 * h3;
      D0 += e0; D1 += e1; D2 += e2; D3 += e3;
      __half2 q;
      float2 f;
      memcpy(&q, &w0, 4); f = __half22float2(q); lx += f.x; ly += f.y;
      memcpy(&q, &w1, 4); f = __half22float2(q); lx += f.x; ly += f.y;
      memcpy(&q, &w2, 4); f = __half22float2(q); lx += f.x; ly += f.y;
      memcpy(&q, &w3, 4); f = __half22float2(q); lx += f.x; ly += f.y;
    }
    for (; e < o1; ++e) {
      uint2 r = eb[e];
      unsigned int w = eaw[e];
      float ex = __uint_as_float(r.y);
      A0 += ex * hld(h16, r.x, l);
      D0 += ex;
      __half2 q;
      memcpy(&q, &w, 4);
      float2 f = __half22float2(q);
      lx += f.x; ly += f.y;
    }
    float acc = (A0 + A1) + (A2 + A3);
    float den = (D0 + D1) + (D2 + D3);
    float dgc = fmaxf((float)(o1 - o0), 1.f);
    float lg = a_s[node] + a_d[node] + (lx * wep[0] + ly * wep[1]) / dgc;
    lg = lg > 0.f ? lg : 0.2f * lg;
    float ex = __expf(lg);
    float hi = __half2float(h16[(size_t)node * C + l]);
    v = fmaxf((acc + ex * hi) / (den + ex) + bias[l], 0.f);
    outv[(size_t)node * C + l] = v;
    if (l == 0) laxlay[node] = make_float2(lx, ly);
  }
  float s = v, q = v * v;
  s += __shfl_down(s, 32); s += __shfl_down(s, 16);
  q += __shfl_down(q, 32); q += __shfl_down(q, 16);
  if ((t & 63) < 16) {
    atomicAdd(&sbn[l], s);
    atomicAdd(&sbn[16 + l], q);
  }
  __syncthreads();
  if (t < 16) atomicAdd(&bnsum[t], sbn[t]);
  else if (t < 32) atomicAdd(&bnsq[t - 16], sbn[t]);
}

// ---- gather L2: same shape, ex from k_exp2, laxlay reused, 8B/edge stream ----
__global__ __launch_bounds__(256) void k_gather2(
    const uint2* __restrict__ eb, const int* __restrict__ offs,
    const float* __restrict__ a_s, const float* __restrict__ a_d,
    const __half* __restrict__ h16,
    const float* __restrict__ wep, const float* __restrict__ bias,
    const float2* __restrict__ laxlay,
    float* __restrict__ outv, int n) {
  int t = threadIdx.x;
  int node = blockIdx.x * 16 + (t >> 4);
  if (node >= n) return;
  int l = t & 15;
  int o0 = offs[node], o1 = offs[node + 1];
  float A0 = 0.f, A1 = 0.f, A2 = 0.f, A3 = 0.f;
  float D0 = 0.f, D1 = 0.f, D2 = 0.f, D3 = 0.f;
  int e = o0;
  for (; e + 4 <= o1; e += 4) {
    uint2 r0 = eb[e], r1 = eb[e + 1], r2 = eb[e + 2], r3 = eb[e + 3];
    float h0 = hld(h16, r0.x, l), h1 = hld(h16, r1.x, l);
    float h2 = hld(h16, r2.x, l), h3 = hld(h16, r3.x, l);
    float e0 = __uint_as_float(r0.y), e1 = __uint_as_float(r1.y);
    float e2 = __uint_as_float(r2.y), e3 = __uint_as_float(r3.y);
    A0 += e0 * h0; A1 += e1 * h1; A2 += e2 * h2; A3 += e3 * h3;
    D0 += e0; D1 += e1; D2 += e2; D3 += e3;
  }
  for (; e < o1; ++e) {
    uint2 r = eb[e];
    float ex = __uint_as_float(r.y);
    A0 += ex * hld(h16, r.x, l);
    D0 += ex;
  }
  float acc = (A0 + A1) + (A2 + A3);
  float den = (D0 + D1) + (D2 + D3);
  float2 ll = laxlay[node];
  float dgc = fmaxf((float)(o1 - o0), 1.f);
  float lg = a_s[node] + a_d[node] + (ll.x * wep[0] + ll.y * wep[1]) / dgc;
  lg = lg > 0.f ? lg : 0.2f * lg;
  float ex = __expf(lg);
  float hi = __half2float(h16[(size_t)node * C + l]);
  float v = fmaxf((acc + ex * hi) / (den + ex) + bias[l], 0.f);
  outv[(size_t)node * C + l] = v;
}

__global__ void k_bnp(const float* __restrict__ bnsum, const float* __restrict__ bnsq,
                      const float* __restrict__ g, const float* __restrict__ bb,
                      float* __restrict__ scale, float* __restrict__ shift, float invn) {
  int c = threadIdx.x;
  if (c >= C) return;
  float mean = bnsum[c] * invn;
  float var = bnsq[c] * invn - mean * mean;
  float s = g[c] * rsqrtf(var + 1e-5f);
  scale[c] = s; shift[c] = bb[c] - mean * s;
}

// ---------------- BN + 16x16 matmul + a_s/a_d for layer 2; h out fp16 ----------------
__global__ __launch_bounds__(256) void k_node2(
    const float* __restrict__ outv, const float* __restrict__ scale,
    const float* __restrict__ shift, const float* __restrict__ W2,
    const float* __restrict__ asw, const float* __restrict__ adw,
    __half* __restrict__ h16, float* __restrict__ a_s, float* __restrict__ a_d, int n) {
  __shared__ float w2s[C * C];
  if (threadIdx.x < C * C) w2s[threadIdx.x] = W2[threadIdx.x];
  __syncthreads();
  int i = blockIdx.x * 256 + threadIdx.x;
  if (i >= n) return;
  float hn[C];
  #pragma unroll
  for (int c = 0; c < C; ++c) hn[c] = outv[(size_t)i * C + c] * scale[c] + shift[c];
  float h2[C];
  #pragma unroll
  for (int j = 0; j < C; ++j) {
    float acc = 0.f;
    #pragma unroll
    for (int c = 0; c < C; ++c) acc += hn[c] * w2s[c * C + j];
    h2[j] = acc;
  }
  float hs = 0.f, hd = 0.f;
  #pragma unroll
  for (int j = 0; j < C; ++j) { hs += h2[j] * asw[j]; hd += h2[j] * adw[j]; }
  a_s[i] = hs; a_d[i] = hd;
  union { uint4 u; __half2 p[4]; } A, Bu;
  A.p[0] = __floats2half2_rn(h2[0], h2[1]);  A.p[1] = __floats2half2_rn(h2[2], h2[3]);
  A.p[2] = __floats2half2_rn(h2[4], h2[5]);  A.p[3] = __floats2half2_rn(h2[6], h2[7]);
  Bu.p[0] = __floats2half2_rn(h2[8], h2[9]);  Bu.p[1] = __floats2half2_rn(h2[10], h2[11]);
  Bu.p[2] = __floats2half2_rn(h2[12], h2[13]); Bu.p[3] = __floats2half2_rn(h2[14], h2[15]);
  uint4* hp = (uint4*)(h16 + (size_t)i * C);
  hp[0] = A.u; hp[1] = Bu.u;
}

// ---------------- graph segment offsets ----------------
__global__ void k_gstart(const int* __restrict__ batch, int* __restrict__ gs,
                         int n, int B_) {
  int g = blockIdx.x * blockDim.x + threadIdx.x;
  if (g > B_) return;
  if (g == B_) { gs[B_] = n; return; }
  int lo = 0, hi = n;
  while (lo < hi) { int mid = (lo + hi) >> 1; if (batch[mid] < g) lo = mid + 1; else hi = mid; }
  gs[g] = lo;
}

__global__ __launch_bounds__(256) void k_xe(
    const float* __restrict__ outv, const int* __restrict__ gs,
    float* __restrict__ xe, int B_) {
  int wave = blockIdx.x * 4 + (threadIdx.x >> 6);
  if (wave >= B_) return;
  int lane = threadIdx.x & 63;
  int c = lane & 15, sub = lane >> 4;
  int base = gs[wave], end = gs[wave + 1];
  float s = 0.f;
  for (int n0 = base + sub; n0 < end; n0 += 4) s += outv[(size_t)n0 * C + c];
  s += __shfl_down(s, 32);
  s += __shfl_down(s, 16);
  if (lane < 16) xe[(size_t)wave * C + c] = s / fmaxf((float)(end - base), 1.f);
}

// ---------------- D2RL tail: BN/MLP stages only ----------------
__global__ __launch_bounds__(512) void k_tail_z3(
    const float* __restrict__ xe_in,
    const float* __restrict__ gL1, const float* __restrict__ bL1,
    const float* __restrict__ Wl1, const float* __restrict__ bl1,
    const float* __restrict__ gL2, const float* __restrict__ bL2,
    const float* __restrict__ Wl2, const float* __restrict__ bl2,
    const float* __restrict__ gL3, const float* __restrict__ bL3,
    const float* __restrict__ Wl3, const float* __restrict__ bl3,
    float* __restrict__ z3buf, int B_) {
  __shared__ float ssum[2 * C], ssq[2 * C], sc[2 * C], sh[2 * C];
  int t = threadIdx.x;
  float invB = 1.f / (float)B_;
  float xe[C];
  #pragma unroll
  for (int c = 0; c < C; ++c) xe[c] = xe_in[(size_t)t * C + c];

  if (t < 2 * C) { ssum[t] = 0.f; ssq[t] = 0.f; }
  __syncthreads();
  #pragma unroll
  for (int c = 0; c < C; ++c) {
    float s = xe[c], q = xe[c] * xe[c];
    for (int o = 32; o > 0; o >>= 1) { s += __shfl_down(s, o); q += __shfl_down(q, o); }
    if ((t & 63) == 0) { atomicAdd(&ssum[c], s); atomicAdd(&ssq[c], q); }
  }
  __syncthreads();
  if (t < C) {
    float mean = ssum[t] * invB, var = ssq[t] * invB - mean * mean;
    float s = gL1[t] * rsqrtf(var + 1e-5f);
    sc[t] = s; sh[t] = bL1[t] - mean * s;
  }
  __syncthreads();
  float z[C];
  #pragma unroll
  for (int j = 0; j < C; ++j) {
    float acc = bl1[j];
    #pragma unroll
    for (int c = 0; c < C; ++c) acc += (xe[c] * sc[c] + sh[c]) * Wl1[c * C + j];
    z[j] = fmaxf(acc, 0.f);
  }
  __syncthreads();

  if (t < 2 * C) { ssum[t] = 0.f; ssq[t] = 0.f; }
  __syncthreads();
  #pragma unroll
  for (int c = 0; c < C; ++c) {
    float s = z[c], q = z[c] * z[c];
    for (int o = 32; o > 0; o >>= 1) { s += __shfl_down(s, o); q += __shfl_down(q, o); }
    if ((t & 63) == 0) { atomicAdd(&ssum[c], s); atomicAdd(&ssq[c], q); }
    float s2 = xe[c], q2 = xe[c] * xe[c];
    for (int o = 32; o > 0; o >>= 1) { s2 += __shfl_down(s2, o); q2 += __shfl_down(q2, o); }
    if ((t & 63) == 0) { atomicAdd(&ssum[C + c], s2); atomicAdd(&ssq[C + c], q2); }
  }
  __syncthreads();
  if (t < 2 * C) {
    float mean = ssum[t] * invB, var = ssq[t] * invB - mean * mean;
    float s = gL2[t] * rsqrtf(var + 1e-5f);
    sc[t] = s; sh[t] = bL2[t] - mean * s;
  }
  __syncthreads();
  float z2[C];
  #pragma unroll
  for (int j = 0; j < C; ++j) {
    float acc = bl2[j];
    #pragma unroll
    for (int c = 0; c < C; ++c) acc += (z[c] * sc[c] + sh[c]) * Wl2[c * C + j];
    #pragma unroll
    for (int c = 0; c < C; ++c) acc += (xe[c] * sc[C + c] + sh[C + c]) * Wl2[(C + c) * C + j];
    z2[j] = fmaxf(acc, 0.f);
  }
  __syncthreads();

  if (t < 2 * C) { ssum[t] = 0.f; ssq[t] = 0.f; }
  __syncthreads();
  #pragma unroll
  for (int c = 0; c < C; ++c) {
    float s = z2[c], q = z2[c] * z2[c];
    for (int o = 32; o > 0; o >>= 1) { s += __shfl_down(s, o); q += __shfl_down(q, o); }
    if ((t & 63) == 0) { atomicAdd(&ssum[c], s); atomicAdd(&ssq[c], q); }
    float s2 = xe[c], q2 = xe[c] * xe[c];
    for (int o = 32; o > 0; o >>= 1) { s2 += __shfl_down(s2, o); q2 += __shfl_down(q2, o); }
    if ((t & 63) == 0) { atomicAdd(&ssum[C + c], s2); atomicAdd(&ssq[C + c], q2); }
  }
  __syncthreads();
  if (t < 2 * C) {
    float mean = ssum[t] * invB, var = ssq[t] * invB - mean * mean;
    float s = gL3[t] * rsqrtf(var + 1e-5f);
    sc[t] = s; sh[t] = bL3[t] - mean * s;
  }
  __syncthreads();
  #pragma unroll
  for (int j = 0; j < C; ++j) {
    float acc = bl3[j];
    #pragma unroll
    for (int c = 0; c < C; ++c) acc += (z2[c] * sc[c] + sh[c]) * Wl3[c * C + j];
    #pragma unroll
    for (int c = 0; c < C; ++c) acc += (xe[c] * sc[C + c] + sh[C + c]) * Wl3[(C + c) * C + j];
    z3buf[(size_t)t * C + j] = fmaxf(acc, 0.f);
  }
}

// ---------------- heads: one wave per graph ----------------
__global__ __launch_bounds__(256) void k_heads(
    const float* __restrict__ z3buf,
    const float* __restrict__ Wx, const float* __restrict__ bx,
    const float* __restrict__ Wy, const float* __restrict__ by,
    const float* __restrict__ Wr, const float* __restrict__ br,
    float* __restrict__ out, int B_) {
  int wv = blockIdx.x * 4 + (threadIdx.x >> 6);
  if (wv >= B_) return;
  int lane = threadIdx.x & 63;
  float z[C];
  #pragma unroll
  for (int c = 0; c < C; ++c) z[c] = z3buf[(size_t)wv * C + c];

  float ax = bx[lane];
  #pragma unroll
  for (int c = 0; c < C; ++c) ax += z[c] * Wx[c * 64 + lane];
  float m = ax;
  #pragma unroll
  for (int o = 32; o > 0; o >>= 1) m = fmaxf(m, __shfl_xor(m, o));
  float e = __expf(ax - m);
  float s = e;
  #pragma unroll
  for (int o = 32; o > 0; o >>= 1) s += __shfl_xor(s, o);
  out[(size_t)wv * 64 + lane] = e / s;

  float ay = by[lane];
  #pragma unroll
  for (int c = 0; c < C; ++c) ay += z[c] * Wy[c * 64 + lane];
  m = ay;
  #pragma unroll
  for (int o = 32; o > 0; o >>= 1) m = fmaxf(m, __shfl_xor(m, o));
  e = __expf(ay - m);
  s = e;
  #pragma unroll
  for (int o = 32; o > 0; o >>= 1) s += __shfl_xor(s, o);
  out[(size_t)B_ * 64 + (size_t)wv * 64 + lane] = e / s;

  if (lane < 4) {
    float ar = br[lane];
    #pragma unroll
    for (int c = 0; c < C; ++c) ar += z[c] * Wr[c * 4 + lane];
    float mr = ar;
    mr = fmaxf(mr, __shfl_xor(mr, 1));
    mr = fmaxf(mr, __shfl_xor(mr, 2));
    float er = __expf(ar - mr);
    float sr = er;
    sr += __shfl_xor(sr, 1);
    sr += __shfl_xor(sr, 2);
    out[(size_t)B_ * 128 + (size_t)wv * 4 + lane] = er / sr;
  }
}

extern "C" void kernel_launch(void* const* d_in, const int* in_sizes, int n_in,
                              void* d_out, int out_size, void* d_ws, size_t ws_size,
                              hipStream_t stream) {
  const float* x     = (const float*)d_in[0];
  const int*   eidx  = (const int*)d_in[1];
  const float* eattr = (const float*)d_in[2];
  const int*   batch = (const int*)d_in[3];
  const float* W1  = (const float*)d_in[4];
  const float* We1 = (const float*)d_in[5];
  const float* as1 = (const float*)d_in[6];
  const float* ad1 = (const float*)d_in[7];
  const float* ae1 = (const float*)d_in[8];
  const float* b1  = (const float*)d_in[9];
  const float* g1  = (const float*)d_in[10];
  const float* bb1 = (const float*)d_in[11];
  const float* W2  = (const float*)d_in[12];
  const float* We2 = (const float*)d_in[13];
  const float* as2 = (const float*)d_in[14];
  const float* ad2 = (const float*)d_in[15];
  const float* ae2 = (const float*)d_in[16];
  const float* b2  = (const float*)d_in[17];
  const float* gL1 = (const float*)d_in[18];
  const float* bL1 = (const float*)d_in[19];
  const float* Wl1 = (const float*)d_in[20];
  const float* bl1 = (const float*)d_in[21];
  const float* gL2 = (const float*)d_in[22];
  const float* bL2 = (const float*)d_in[23];
  const float* Wl2 = (const float*)d_in[24];
  const float* bl2 = (const float*)d_in[25];
  const float* gL3 = (const float*)d_in[26];
  const float* bL3 = (const float*)d_in[27];
  const float* Wl3 = (const float*)d_in[28];
  const float* bl3 = (const float*)d_in[29];
  const float* Wx  = (const float*)d_in[30];
  const float* bx  = (const float*)d_in[31];
  const float* Wy  = (const float*)d_in[32];
  const float* by  = (const float*)d_in[33];
  const float* Wr  = (const float*)d_in[34];
  const float* br  = (const float*)d_in[35];

  int N = in_sizes[3];
  int E = in_sizes[2] / 2;
  int B = out_size / 132;
  int nblk = (N + 511) / 512;

  char* w = (char*)d_ws;
  size_t o = 0;
  auto alloc = [&](size_t bytes) { char* p = w + o; o += (bytes + 15) & ~15ull; return p; };
  uint2*  eb     = (uint2*)alloc((size_t)E * 8);
  unsigned int* eaw = (unsigned int*)alloc((size_t)E * 4);
  int*    dstb   = (int*)alloc((size_t)E * 4);
  int*    rank   = (int*)alloc((size_t)E * 4);
  __half* h16    = (__half*)alloc((size_t)N * C * 2);
  float*  outv   = (float*)alloc((size_t)N * C * 4);
  float*  a_s    = (float*)alloc((size_t)N * 4);
  float*  a_d    = (float*)alloc((size_t)N * 4);
  float2* laxlay = (float2*)alloc((size_t)N * 8);
  int*    counts = (int*)alloc((size_t)N * 4);
  int*    offs   = (int*)alloc((size_t)(N + 4) * 4);
  int*    bsum   = (int*)alloc((size_t)(nblk + 4) * 4);
  float*  bn     = (float*)alloc(64 * 4);
  float*  wep    = (float*)alloc(16 * 4);
  float*  xe     = (float*)alloc((size_t)B * C * 4);
  int*    gs     = (int*)alloc((size_t)(B + 4) * 4);
  float*  z3buf  = (float*)alloc((size_t)B * C * 4);

  const int* src = eidx;
  const int* dst = eidx + E;
  int ebl = (E + 255) / 256;
  int nbl = (N + 255) / 256;
  int gbl = (N + 15) / 16;

  hipMemsetAsync(counts, 0, (size_t)N * 4, stream);
  hipMemsetAsync(bn, 0, 32 * 4, stream);

  k_prep<<<1, 64, 0, stream>>>(We1, ae1, We2, ae2, wep);
  k_gemm1<<<(N + 63) / 64, 256, 0, stream>>>(x, W1, as1, ad1, h16, a_s, a_d, N);
  k_hist_rank<<<ebl, 256, 0, stream>>>(dst, counts, rank, E);
  k_scan1<<<nblk, 512, 0, stream>>>(counts, bsum, N);
  k_scan2<<<1, 512, 0, stream>>>(bsum, offs, nblk, N);
  k_scan3<<<nblk, 512, 0, stream>>>(counts, bsum, offs, N);
  k_scatter<<<ebl, 256, 0, stream>>>(src, dst, (const float2*)eattr, offs, rank,
                                     a_s, a_d, wep, eb, eaw, dstb, E);
  k_gather1<<<gbl, 256, 0, stream>>>(eb, eaw, offs, a_s, a_d, h16, wep, b1,
                                     outv, laxlay, bn, bn + 16, N);
  k_bnp<<<1, 64, 0, stream>>>(bn, bn + 16, g1, bb1, bn + 32, bn + 48, 1.f / (float)N);
  k_node2<<<nbl, 256, 0, stream>>>(outv, bn + 32, bn + 48, W2, as2, ad2, h16, a_s, a_d, N);
  k_exp2<<<ebl, 256, 0, stream>>>(eb, eaw, dstb, a_s, a_d, wep + 2, E);
  k_gather2<<<gbl, 256, 0, stream>>>(eb, offs, a_s, a_d, h16, wep + 2, b2,
                                     laxlay, outv, N);
  k_gstart<<<(B + 1 + 255) / 256, 256, 0, stream>>>(batch, gs, N, B);
  k_xe<<<(B + 3) / 4, 256, 0, stream>>>(outv, gs, xe, B);
  k_tail_z3<<<1, B, 0, stream>>>(xe, gL1, bL1, Wl1, bl1, gL2, bL2, Wl2, bl2,
                                 gL3, bL3, Wl3, bl3, z3buf, B);
  k_heads<<<(B + 3) / 4, 256, 0, stream>>>(z3buf, Wx, bx, Wy, by, Wr, br,
                                           (float*)d_out, B);
}

// Round 9
// 835.272 us; speedup vs baseline: 1.7016x; 1.1727x over previous
//
#include <hip/hip_runtime.h>
#include <hip/hip_fp16.h>
#include <math.h>

#define C 16
#define FIN 128

__device__ __forceinline__ float hld(const __half* __restrict__ h16, unsigned int s, int l) {
  return __half2float(h16[(size_t)s * C + l]);
}

// ---------------- GEMM x@W1 + fused a_s/a_d; h stored fp16 ----------------
__global__ __launch_bounds__(256) void k_gemm1(
    const float* __restrict__ x, const float* __restrict__ W,
    const float* __restrict__ asw, const float* __restrict__ adw,
    __half* __restrict__ h16, float* __restrict__ a_s, float* __restrict__ a_d, int n) {
  __shared__ float xs[64 * 129];
  __shared__ float Ws[FIN * C];
  __shared__ float pAs[4][64], pAd[4][64];
  int t = threadIdx.x;
  int node0 = blockIdx.x * 64;
  for (int i = t; i < FIN * C; i += 256) Ws[i] = W[i];
  for (int i = t; i < 64 * FIN; i += 256) {
    int r = i >> 7, c = i & 127;
    int node = node0 + r;
    xs[r * 129 + c] = (node < n) ? x[(size_t)node * FIN + c] : 0.f;
  }
  __syncthreads();
  int nn = t & 63, cg = (t >> 6) * 4, grp = t >> 6;
  float a0 = 0.f, a1 = 0.f, a2 = 0.f, a3 = 0.f;
  const float* xr = &xs[nn * 129];
  #pragma unroll 8
  for (int k = 0; k < FIN; ++k) {
    float xv = xr[k];
    const float* wr = &Ws[k * C + cg];
    a0 += xv * wr[0]; a1 += xv * wr[1]; a2 += xv * wr[2]; a3 += xv * wr[3];
  }
  int node = node0 + nn;
  if (node < n) {
    __half2 p0 = __floats2half2_rn(a0, a1), p1 = __floats2half2_rn(a2, a3);
    uint2 wv;
    memcpy(&wv.x, &p0, 4); memcpy(&wv.y, &p1, 4);
    *(uint2*)&h16[(size_t)node * C + cg] = wv;
  }
  pAs[grp][nn] = a0 * asw[cg] + a1 * asw[cg + 1] + a2 * asw[cg + 2] + a3 * asw[cg + 3];
  pAd[grp][nn] = a0 * adw[cg] + a1 * adw[cg + 1] + a2 * adw[cg + 2] + a3 * adw[cg + 3];
  __syncthreads();
  if (t < 64 && node0 + t < n) {
    a_s[node0 + t] = pAs[0][t] + pAs[1][t] + pAs[2][t] + pAs[3][t];
    a_d[node0 + t] = pAd[0][t] + pAd[1][t] + pAd[2][t] + pAd[3][t];
  }
}

// ---------------- tiny prep: We·ae dot for both layers ----------------
__global__ void k_prep(const float* __restrict__ We1, const float* __restrict__ ae1,
                       const float* __restrict__ We2, const float* __restrict__ ae2,
                       float* __restrict__ wep) {
  if (threadIdx.x == 0) {
    float a = 0.f, b = 0.f, c = 0.f, d = 0.f;
    for (int i = 0; i < C; ++i) {
      a += We1[i] * ae1[i]; b += We1[C + i] * ae1[i];
      c += We2[i] * ae2[i]; d += We2[C + i] * ae2[i];
    }
    wep[0] = a; wep[1] = b; wep[2] = c; wep[3] = d;
  }
}

// ---------------- CSR build ----------------
__global__ __launch_bounds__(256) void k_hist_rank(
    const int* __restrict__ dst, int* __restrict__ counts,
    int* __restrict__ rank, int ne) {
  int e = blockIdx.x * 256 + threadIdx.x;
  if (e < ne) rank[e] = atomicAdd(&counts[dst[e]], 1);
}

__global__ __launch_bounds__(512) void k_scan1(const int* __restrict__ counts,
                                               int* __restrict__ bsum, int n) {
  __shared__ int sd[512];
  int i = blockIdx.x * 512 + threadIdx.x;
  sd[threadIdx.x] = (i < n) ? counts[i] : 0;
  __syncthreads();
  for (int s = 256; s > 0; s >>= 1) {
    if (threadIdx.x < s) sd[threadIdx.x] += sd[threadIdx.x + s];
    __syncthreads();
  }
  if (threadIdx.x == 0) bsum[blockIdx.x] = sd[0];
}

__global__ __launch_bounds__(512) void k_scan2(int* __restrict__ bsum,
                                               int* __restrict__ offs,
                                               int nblk, int n) {
  __shared__ int sd[512];
  int t = threadIdx.x;
  int v = (t < nblk) ? bsum[t] : 0;
  sd[t] = v;
  __syncthreads();
  for (int off = 1; off < 512; off <<= 1) {
    int x = (t >= off) ? sd[t - off] : 0;
    __syncthreads();
    sd[t] += x;
    __syncthreads();
  }
  if (t < nblk) bsum[t] = sd[t] - v;
  if (t == nblk - 1) offs[n] = sd[t];
}

__global__ __launch_bounds__(512) void k_scan3(const int* __restrict__ counts,
                                               const int* __restrict__ bsum,
                                               int* __restrict__ offs, int n) {
  __shared__ int sd[512];
  int t = threadIdx.x;
  int i = blockIdx.x * 512 + t;
  int v = (i < n) ? counts[i] : 0;
  sd[t] = v;
  __syncthreads();
  for (int off = 1; off < 512; off <<= 1) {
    int x = (t >= off) ? sd[t - off] : 0;
    __syncthreads();
    sd[t] += x;
    __syncthreads();
  }
  if (i < n) offs[i] = bsum[blockIdx.x] + sd[t] - v;
}

// scatter: single 16B record per edge: {src, ex1, ea_half2, 0}
__global__ __launch_bounds__(256) void k_scatter(
    const int* __restrict__ src, const int* __restrict__ dst,
    const float2* __restrict__ ea, const int* __restrict__ offs,
    const int* __restrict__ rank,
    const float* __restrict__ a_s, const float* __restrict__ a_d,
    const float* __restrict__ wep,
    uint4* __restrict__ ebuf, int ne) {
  int e = blockIdx.x * 256 + threadIdx.x;
  if (e >= ne) return;
  int s = src[e], d = dst[e];
  float2 a = ea[e];
  float lg = a_s[s] + a_d[d] + a.x * wep[0] + a.y * wep[1];
  lg = lg > 0.f ? lg : 0.2f * lg;
  float ex = __expf(lg);
  __half2 hh = __floats2half2_rn(a.x, a.y);
  unsigned int hb;
  memcpy(&hb, &hh, 4);
  ebuf[offs[d] + rank[e]] = make_uint4((unsigned int)s, __float_as_uint(ex), hb, 0u);
}

// ---- gather L1: 16 lanes/node broadcast form, manual 4x unroll ----
__global__ __launch_bounds__(256) void k_gather1(
    const uint4* __restrict__ ebuf, const int* __restrict__ offs,
    const float* __restrict__ a_s, const float* __restrict__ a_d,
    const __half* __restrict__ h16,
    const float* __restrict__ wep, const float* __restrict__ bias,
    float* __restrict__ outv, float2* __restrict__ laxlay,
    float* __restrict__ bnsum, float* __restrict__ bnsq, int n) {
  __shared__ float sbn[32];
  int t = threadIdx.x;
  if (t < 32) sbn[t] = 0.f;
  __syncthreads();
  int node = blockIdx.x * 16 + (t >> 4);
  int l = t & 15;
  float v = 0.f;
  if (node < n) {
    int o0 = offs[node], o1 = offs[node + 1];
    float A0 = 0.f, A1 = 0.f, A2 = 0.f, A3 = 0.f;
    float D0 = 0.f, D1 = 0.f, D2 = 0.f, D3 = 0.f;
    float lx = 0.f, ly = 0.f;
    int e = o0;
    for (; e + 4 <= o1; e += 4) {
      uint4 r0 = ebuf[e], r1 = ebuf[e + 1], r2 = ebuf[e + 2], r3 = ebuf[e + 3];
      float h0 = hld(h16, r0.x, l), h1 = hld(h16, r1.x, l);
      float h2 = hld(h16, r2.x, l), h3 = hld(h16, r3.x, l);
      float e0 = __uint_as_float(r0.y), e1 = __uint_as_float(r1.y);
      float e2 = __uint_as_float(r2.y), e3 = __uint_as_float(r3.y);
      A0 += e0 * h0; A1 += e1 * h1; A2 += e2 * h2; A3 += e3 * h3;
      D0 += e0; D1 += e1; D2 += e2; D3 += e3;
      __half2 q; float2 f;
      memcpy(&q, &r0.z, 4); f = __half22float2(q); lx += f.x; ly += f.y;
      memcpy(&q, &r1.z, 4); f = __half22float2(q); lx += f.x; ly += f.y;
      memcpy(&q, &r2.z, 4); f = __half22float2(q); lx += f.x; ly += f.y;
      memcpy(&q, &r3.z, 4); f = __half22float2(q); lx += f.x; ly += f.y;
    }
    for (; e < o1; ++e) {
      uint4 r = ebuf[e];
      float ex = __uint_as_float(r.y);
      A0 += ex * hld(h16, r.x, l);
      D0 += ex;
      __half2 q;
      memcpy(&q, &r.z, 4);
      float2 f = __half22float2(q);
      lx += f.x; ly += f.y;
    }
    float acc = (A0 + A1) + (A2 + A3);
    float den = (D0 + D1) + (D2 + D3);
    float dgc = fmaxf((float)(o1 - o0), 1.f);
    float lg = a_s[node] + a_d[node] + (lx * wep[0] + ly * wep[1]) / dgc;
    lg = lg > 0.f ? lg : 0.2f * lg;
    float ex = __expf(lg);
    float hi = __half2float(h16[(size_t)node * C + l]);
    v = fmaxf((acc + ex * hi) / (den + ex) + bias[l], 0.f);
    outv[(size_t)node * C + l] = v;
    if (l == 0) laxlay[node] = make_float2(lx, ly);
  }
  float s = v, q = v * v;
  s += __shfl_down(s, 32); s += __shfl_down(s, 16);
  q += __shfl_down(q, 32); q += __shfl_down(q, 16);
  if ((t & 63) < 16) {
    atomicAdd(&sbn[l], s);
    atomicAdd(&sbn[16 + l], q);
  }
  __syncthreads();
  if (t < 16) atomicAdd(&bnsum[t], sbn[t]);
  else if (t < 32) atomicAdd(&bnsq[t - 16], sbn[t]);
}

// ---- gather L2: inline ex2 = exp(lrelu(a_s2[src]+a_d2[node]+ea.we2)) ----
__global__ __launch_bounds__(256) void k_gather2(
    const uint4* __restrict__ ebuf, const int* __restrict__ offs,
    const float* __restrict__ a_s, const float* __restrict__ a_d,
    const __half* __restrict__ h16,
    const float* __restrict__ wep, const float* __restrict__ bias,
    const float2* __restrict__ laxlay,
    float* __restrict__ outv, int n) {
  int t = threadIdx.x;
  int node = blockIdx.x * 16 + (t >> 4);
  if (node >= n) return;
  int l = t & 15;
  float we0 = wep[0], we1 = wep[1];
  int o0 = offs[node], o1 = offs[node + 1];
  float adi = a_d[node];
  float A0 = 0.f, A1 = 0.f, A2 = 0.f, A3 = 0.f;
  float D0 = 0.f, D1 = 0.f, D2 = 0.f, D3 = 0.f;
  int e = o0;
  for (; e + 4 <= o1; e += 4) {
    uint4 r0 = ebuf[e], r1 = ebuf[e + 1], r2 = ebuf[e + 2], r3 = ebuf[e + 3];
    float s0 = a_s[(int)r0.x], s1 = a_s[(int)r1.x];
    float s2 = a_s[(int)r2.x], s3 = a_s[(int)r3.x];
    float h0 = hld(h16, r0.x, l), h1 = hld(h16, r1.x, l);
    float h2 = hld(h16, r2.x, l), h3 = hld(h16, r3.x, l);
    __half2 q; float2 f;
    memcpy(&q, &r0.z, 4); f = __half22float2(q);
    float g0 = s0 + adi + f.x * we0 + f.y * we1;
    memcpy(&q, &r1.z, 4); f = __half22float2(q);
    float g1 = s1 + adi + f.x * we0 + f.y * we1;
    memcpy(&q, &r2.z, 4); f = __half22float2(q);
    float g2 = s2 + adi + f.x * we0 + f.y * we1;
    memcpy(&q, &r3.z, 4); f = __half22float2(q);
    float g3 = s3 + adi + f.x * we0 + f.y * we1;
    g0 = g0 > 0.f ? g0 : 0.2f * g0; g1 = g1 > 0.f ? g1 : 0.2f * g1;
    g2 = g2 > 0.f ? g2 : 0.2f * g2; g3 = g3 > 0.f ? g3 : 0.2f * g3;
    float e0 = __expf(g0), e1 = __expf(g1), e2 = __expf(g2), e3 = __expf(g3);
    A0 += e0 * h0; A1 += e1 * h1; A2 += e2 * h2; A3 += e3 * h3;
    D0 += e0; D1 += e1; D2 += e2; D3 += e3;
  }
  for (; e < o1; ++e) {
    uint4 r = ebuf[e];
    __half2 q;
    memcpy(&q, &r.z, 4);
    float2 f = __half22float2(q);
    float g = a_s[(int)r.x] + adi + f.x * we0 + f.y * we1;
    g = g > 0.f ? g : 0.2f * g;
    float ex = __expf(g);
    A0 += ex * hld(h16, r.x, l);
    D0 += ex;
  }
  float acc = (A0 + A1) + (A2 + A3);
  float den = (D0 + D1) + (D2 + D3);
  float2 ll = laxlay[node];
  float dgc = fmaxf((float)(o1 - o0), 1.f);
  float lg = a_s[node] + adi + (ll.x * we0 + ll.y * we1) / dgc;
  lg = lg > 0.f ? lg : 0.2f * lg;
  float ex = __expf(lg);
  float hi = __half2float(h16[(size_t)node * C + l]);
  float v = fmaxf((acc + ex * hi) / (den + ex) + bias[l], 0.f);
  outv[(size_t)node * C + l] = v;
}

__global__ void k_bnp(const float* __restrict__ bnsum, const float* __restrict__ bnsq,
                      const float* __restrict__ g, const float* __restrict__ bb,
                      float* __restrict__ scale, float* __restrict__ shift, float invn) {
  int c = threadIdx.x;
  if (c >= C) return;
  float mean = bnsum[c] * invn;
  float var = bnsq[c] * invn - mean * mean;
  float s = g[c] * rsqrtf(var + 1e-5f);
  scale[c] = s; shift[c] = bb[c] - mean * s;
}

// ---------------- BN + 16x16 matmul + a_s/a_d for layer 2; h out fp16 ----------------
__global__ __launch_bounds__(256) void k_node2(
    const float* __restrict__ outv, const float* __restrict__ scale,
    const float* __restrict__ shift, const float* __restrict__ W2,
    const float* __restrict__ asw, const float* __restrict__ adw,
    __half* __restrict__ h16, float* __restrict__ a_s, float* __restrict__ a_d, int n) {
  __shared__ float w2s[C * C];
  if (threadIdx.x < C * C) w2s[threadIdx.x] = W2[threadIdx.x];
  __syncthreads();
  int i = blockIdx.x * 256 + threadIdx.x;
  if (i >= n) return;
  float hn[C];
  #pragma unroll
  for (int c = 0; c < C; ++c) hn[c] = outv[(size_t)i * C + c] * scale[c] + shift[c];
  float h2[C];
  #pragma unroll
  for (int j = 0; j < C; ++j) {
    float acc = 0.f;
    #pragma unroll
    for (int c = 0; c < C; ++c) acc += hn[c] * w2s[c * C + j];
    h2[j] = acc;
  }
  float hs = 0.f, hd = 0.f;
  #pragma unroll
  for (int j = 0; j < C; ++j) { hs += h2[j] * asw[j]; hd += h2[j] * adw[j]; }
  a_s[i] = hs; a_d[i] = hd;
  union { uint4 u; __half2 p[4]; } A, Bu;
  A.p[0] = __floats2half2_rn(h2[0], h2[1]);  A.p[1] = __floats2half2_rn(h2[2], h2[3]);
  A.p[2] = __floats2half2_rn(h2[4], h2[5]);  A.p[3] = __floats2half2_rn(h2[6], h2[7]);
  Bu.p[0] = __floats2half2_rn(h2[8], h2[9]);  Bu.p[1] = __floats2half2_rn(h2[10], h2[11]);
  Bu.p[2] = __floats2half2_rn(h2[12], h2[13]); Bu.p[3] = __floats2half2_rn(h2[14], h2[15]);
  uint4* hp = (uint4*)(h16 + (size_t)i * C);
  hp[0] = A.u; hp[1] = Bu.u;
}

// ---------------- graph segment offsets ----------------
__global__ void k_gstart(const int* __restrict__ batch, int* __restrict__ gs,
                         int n, int B_) {
  int g = blockIdx.x * blockDim.x + threadIdx.x;
  if (g > B_) return;
  if (g == B_) { gs[B_] = n; return; }
  int lo = 0, hi = n;
  while (lo < hi) { int mid = (lo + hi) >> 1; if (batch[mid] < g) lo = mid + 1; else hi = mid; }
  gs[g] = lo;
}

__global__ __launch_bounds__(256) void k_xe(
    const float* __restrict__ outv, const int* __restrict__ gs,
    float* __restrict__ xe, int B_) {
  int wave = blockIdx.x * 4 + (threadIdx.x >> 6);
  if (wave >= B_) return;
  int lane = threadIdx.x & 63;
  int c = lane & 15, sub = lane >> 4;
  int base = gs[wave], end = gs[wave + 1];
  float s = 0.f;
  for (int n0 = base + sub; n0 < end; n0 += 4) s += outv[(size_t)n0 * C + c];
  s += __shfl_down(s, 32);
  s += __shfl_down(s, 16);
  if (lane < 16) xe[(size_t)wave * C + c] = s / fmaxf((float)(end - base), 1.f);
}

// ---------------- D2RL tail: BN/MLP stages only ----------------
__global__ __launch_bounds__(512) void k_tail_z3(
    const float* __restrict__ xe_in,
    const float* __restrict__ gL1, const float* __restrict__ bL1,
    const float* __restrict__ Wl1, const float* __restrict__ bl1,
    const float* __restrict__ gL2, const float* __restrict__ bL2,
    const float* __restrict__ Wl2, const float* __restrict__ bl2,
    const float* __restrict__ gL3, const float* __restrict__ bL3,
    const float* __restrict__ Wl3, const float* __restrict__ bl3,
    float* __restrict__ z3buf, int B_) {
  __shared__ float ssum[2 * C], ssq[2 * C], sc[2 * C], sh[2 * C];
  int t = threadIdx.x;
  float invB = 1.f / (float)B_;
  float xe[C];
  #pragma unroll
  for (int c = 0; c < C; ++c) xe[c] = xe_in[(size_t)t * C + c];

  if (t < 2 * C) { ssum[t] = 0.f; ssq[t] = 0.f; }
  __syncthreads();
  #pragma unroll
  for (int c = 0; c < C; ++c) {
    float s = xe[c], q = xe[c] * xe[c];
    for (int o = 32; o > 0; o >>= 1) { s += __shfl_down(s, o); q += __shfl_down(q, o); }
    if ((t & 63) == 0) { atomicAdd(&ssum[c], s); atomicAdd(&ssq[c], q); }
  }
  __syncthreads();
  if (t < C) {
    float mean = ssum[t] * invB, var = ssq[t] * invB - mean * mean;
    float s = gL1[t] * rsqrtf(var + 1e-5f);
    sc[t] = s; sh[t] = bL1[t] - mean * s;
  }
  __syncthreads();
  float z[C];
  #pragma unroll
  for (int j = 0; j < C; ++j) {
    float acc = bl1[j];
    #pragma unroll
    for (int c = 0; c < C; ++c) acc += (xe[c] * sc[c] + sh[c]) * Wl1[c * C + j];
    z[j] = fmaxf(acc, 0.f);
  }
  __syncthreads();

  if (t < 2 * C) { ssum[t] = 0.f; ssq[t] = 0.f; }
  __syncthreads();
  #pragma unroll
  for (int c = 0; c < C; ++c) {
    float s = z[c], q = z[c] * z[c];
    for (int o = 32; o > 0; o >>= 1) { s += __shfl_down(s, o); q += __shfl_down(q, o); }
    if ((t & 63) == 0) { atomicAdd(&ssum[c], s); atomicAdd(&ssq[c], q); }
    float s2 = xe[c], q2 = xe[c] * xe[c];
    for (int o = 32; o > 0; o >>= 1) { s2 += __shfl_down(s2, o); q2 += __shfl_down(q2, o); }
    if ((t & 63) == 0) { atomicAdd(&ssum[C + c], s2); atomicAdd(&ssq[C + c], q2); }
  }
  __syncthreads();
  if (t < 2 * C) {
    float mean = ssum[t] * invB, var = ssq[t] * invB - mean * mean;
    float s = gL2[t] * rsqrtf(var + 1e-5f);
    sc[t] = s; sh[t] = bL2[t] - mean * s;
  }
  __syncthreads();
  float z2[C];
  #pragma unroll
  for (int j = 0; j < C; ++j) {
    float acc = bl2[j];
    #pragma unroll
    for (int c = 0; c < C; ++c) acc += (z[c] * sc[c] + sh[c]) * Wl2[c * C + j];
    #pragma unroll
    for (int c = 0; c < C; ++c) acc += (xe[c] * sc[C + c] + sh[C + c]) * Wl2[(C + c) * C + j];
    z2[j] = fmaxf(acc, 0.f);
  }
  __syncthreads();

  if (t < 2 * C) { ssum[t] = 0.f; ssq[t] = 0.f; }
  __syncthreads();
  #pragma unroll
  for (int c = 0; c < C; ++c) {
    float s = z2[c], q = z2[c] * z2[c];
    for (int o = 32; o > 0; o >>= 1) { s += __shfl_down(s, o); q += __shfl_down(q, o); }
    if ((t & 63) == 0) { atomicAdd(&ssum[c], s); atomicAdd(&ssq[c], q); }
    float s2 = xe[c], q2 = xe[c] * xe[c];
    for (int o = 32; o > 0; o >>= 1) { s2 += __shfl_down(s2, o); q2 += __shfl_down(q2, o); }
    if ((t & 63) == 0) { atomicAdd(&ssum[C + c], s2); atomicAdd(&ssq[C + c], q2); }
  }
  __syncthreads();
  if (t < 2 * C) {
    float mean = ssum[t] * invB, var = ssq[t] * invB - mean * mean;
    float s = gL3[t] * rsqrtf(var + 1e-5f);
    sc[t] = s; sh[t] = bL3[t] - mean * s;
  }
  __syncthreads();
  #pragma unroll
  for (int j = 0; j < C; ++j) {
    float acc = bl3[j];
    #pragma unroll
    for (int c = 0; c < C; ++c) acc += (z2[c] * sc[c] + sh[c]) * Wl3[c * C + j];
    #pragma unroll
    for (int c = 0; c < C; ++c) acc += (xe[c] * sc[C + c] + sh[C + c]) * Wl3[(C + c) * C + j];
    z3buf[(size_t)t * C + j] = fmaxf(acc, 0.f);
  }
}

// ---------------- heads: one wave per graph ----------------
__global__ __launch_bounds__(256) void k_heads(
    const float* __restrict__ z3buf,
    const float* __restrict__ Wx, const float* __restrict__ bx,
    const float* __restrict__ Wy, const float* __restrict__ by,
    const float* __restrict__ Wr, const float* __restrict__ br,
    float* __restrict__ out, int B_) {
  int wv = blockIdx.x * 4 + (threadIdx.x >> 6);
  if (wv >= B_) return;
  int lane = threadIdx.x & 63;
  float z[C];
  #pragma unroll
  for (int c = 0; c < C; ++c) z[c] = z3buf[(size_t)wv * C + c];

  float ax = bx[lane];
  #pragma unroll
  for (int c = 0; c < C; ++c) ax += z[c] * Wx[c * 64 + lane];
  float m = ax;
  #pragma unroll
  for (int o = 32; o > 0; o >>= 1) m = fmaxf(m, __shfl_xor(m, o));
  float e = __expf(ax - m);
  float s = e;
  #pragma unroll
  for (int o = 32; o > 0; o >>= 1) s += __shfl_xor(s, o);
  out[(size_t)wv * 64 + lane] = e / s;

  float ay = by[lane];
  #pragma unroll
  for (int c = 0; c < C; ++c) ay += z[c] * Wy[c * 64 + lane];
  m = ay;
  #pragma unroll
  for (int o = 32; o > 0; o >>= 1) m = fmaxf(m, __shfl_xor(m, o));
  e = __expf(ay - m);
  s = e;
  #pragma unroll
  for (int o = 32; o > 0; o >>= 1) s += __shfl_xor(s, o);
  out[(size_t)B_ * 64 + (size_t)wv * 64 + lane] = e / s;

  if (lane < 4) {
    float ar = br[lane];
    #pragma unroll
    for (int c = 0; c < C; ++c) ar += z[c] * Wr[c * 4 + lane];
    float mr = ar;
    mr = fmaxf(mr, __shfl_xor(mr, 1));
    mr = fmaxf(mr, __shfl_xor(mr, 2));
    float er = __expf(ar - mr);
    float sr = er;
    sr += __shfl_xor(sr, 1);
    sr += __shfl_xor(sr, 2);
    out[(size_t)B_ * 128 + (size_t)wv * 4 + lane] = er / sr;
  }
}

extern "C" void kernel_launch(void* const* d_in, const int* in_sizes, int n_in,
                              void* d_out, int out_size, void* d_ws, size_t ws_size,
                              hipStream_t stream) {
  const float* x     = (const float*)d_in[0];
  const int*   eidx  = (const int*)d_in[1];
  const float* eattr = (const float*)d_in[2];
  const int*   batch = (const int*)d_in[3];
  const float* W1  = (const float*)d_in[4];
  const float* We1 = (const float*)d_in[5];
  const float* as1 = (const float*)d_in[6];
  const float* ad1 = (const float*)d_in[7];
  const float* ae1 = (const float*)d_in[8];
  const float* b1  = (const float*)d_in[9];
  const float* g1  = (const float*)d_in[10];
  const float* bb1 = (const float*)d_in[11];
  const float* W2  = (const float*)d_in[12];
  const float* We2 = (const float*)d_in[13];
  const float* as2 = (const float*)d_in[14];
  const float* ad2 = (const float*)d_in[15];
  const float* ae2 = (const float*)d_in[16];
  const float* b2  = (const float*)d_in[17];
  const float* gL1 = (const float*)d_in[18];
  const float* bL1 = (const float*)d_in[19];
  const float* Wl1 = (const float*)d_in[20];
  const float* bl1 = (const float*)d_in[21];
  const float* gL2 = (const float*)d_in[22];
  const float* bL2 = (const float*)d_in[23];
  const float* Wl2 = (const float*)d_in[24];
  const float* bl2 = (const float*)d_in[25];
  const float* gL3 = (const float*)d_in[26];
  const float* bL3 = (const float*)d_in[27];
  const float* Wl3 = (const float*)d_in[28];
  const float* bl3 = (const float*)d_in[29];
  const float* Wx  = (const float*)d_in[30];
  const float* bx  = (const float*)d_in[31];
  const float* Wy  = (const float*)d_in[32];
  const float* by  = (const float*)d_in[33];
  const float* Wr  = (const float*)d_in[34];
  const float* br  = (const float*)d_in[35];

  int N = in_sizes[3];
  int E = in_sizes[2] / 2;
  int B = out_size / 132;
  int nblk = (N + 511) / 512;

  char* w = (char*)d_ws;
  size_t o = 0;
  auto alloc = [&](size_t bytes) { char* p = w + o; o += (bytes + 15) & ~15ull; return p; };
  uint4*  ebuf   = (uint4*)alloc((size_t)E * 16);
  int*    rank   = (int*)alloc((size_t)E * 4);
  __half* h16    = (__half*)alloc((size_t)N * C * 2);
  float*  outv   = (float*)alloc((size_t)N * C * 4);
  float*  a_s    = (float*)alloc((size_t)N * 4);
  float*  a_d    = (float*)alloc((size_t)N * 4);
  float2* laxlay = (float2*)alloc((size_t)N * 8);
  int*    counts = (int*)alloc((size_t)N * 4);
  int*    offs   = (int*)alloc((size_t)(N + 4) * 4);
  int*    bsum   = (int*)alloc((size_t)(nblk + 4) * 4);
  float*  bn     = (float*)alloc(64 * 4);
  float*  wep    = (float*)alloc(16 * 4);
  float*  xe     = (float*)alloc((size_t)B * C * 4);
  int*    gs     = (int*)alloc((size_t)(B + 4) * 4);
  float*  z3buf  = (float*)alloc((size_t)B * C * 4);

  const int* src = eidx;
  const int* dst = eidx + E;
  int ebl = (E + 255) / 256;
  int nbl = (N + 255) / 256;
  int gbl = (N + 15) / 16;

  hipMemsetAsync(counts, 0, (size_t)N * 4, stream);
  hipMemsetAsync(bn, 0, 32 * 4, stream);

  k_prep<<<1, 64, 0, stream>>>(We1, ae1, We2, ae2, wep);
  k_gemm1<<<(N + 63) / 64, 256, 0, stream>>>(x, W1, as1, ad1, h16, a_s, a_d, N);
  k_hist_rank<<<ebl, 256, 0, stream>>>(dst, counts, rank, E);
  k_scan1<<<nblk, 512, 0, stream>>>(counts, bsum, N);
  k_scan2<<<1, 512, 0, stream>>>(bsum, offs, nblk, N);
  k_scan3<<<nblk, 512, 0, stream>>>(counts, bsum, offs, N);
  k_scatter<<<ebl, 256, 0, stream>>>(src, dst, (const float2*)eattr, offs, rank,
                                     a_s, a_d, wep, ebuf, E);
  k_gather1<<<gbl, 256, 0, stream>>>(ebuf, offs, a_s, a_d, h16, wep, b1,
                                     outv, laxlay, bn, bn + 16, N);
  k_bnp<<<1, 64, 0, stream>>>(bn, bn + 16, g1, bb1, bn + 32, bn + 48, 1.f / (float)N);
  k_node2<<<nbl, 256, 0, stream>>>(outv, bn + 32, bn + 48, W2, as2, ad2, h16, a_s, a_d, N);
  k_gather2<<<gbl, 256, 0, stream>>>(ebuf, offs, a_s, a_d, h16, wep + 2, b2,
                                     laxlay, outv, N);
  k_gstart<<<(B + 1 + 255) / 256, 256, 0, stream>>>(batch, gs, N, B);
  k_xe<<<(B + 3) / 4, 256, 0, stream>>>(outv, gs, xe, B);
  k_tail_z3<<<1, B, 0, stream>>>(xe, gL1, bL1, Wl1, bl1, gL2, bL2, Wl2, bl2,
                                 gL3, bL3, Wl3, bl3, z3buf, B);
  k_heads<<<(B + 3) / 4, 256, 0, stream>>>(z3buf, Wx, bx, Wy, by, Wr, br,
                                           (float*)d_out, B);
}